// Round 1
// 475.973 us; speedup vs baseline: 1.0438x; 1.0438x over previous
//
#include <hip/hip_runtime.h>
#include <hip/hip_bf16.h>
#include <cstdint>

typedef unsigned short u16;
typedef unsigned int   u32;
typedef __bf16 bf16x8 __attribute__((ext_vector_type(8)));
typedef float  f32x4  __attribute__((ext_vector_type(4)));

#define S_    512
#define D_    128
#define H_    128
#define NPOS_ (S_ * S_)      // 262144 rows
#define LN_EPS 1e-5f

// ---------- small helpers ----------
__device__ __forceinline__ u16 f2bf(float f) {
  union { __hip_bfloat16 h; u16 u; } cv;
  cv.h = __float2bfloat16(f);
  return cv.u;
}
__device__ __forceinline__ float bflo(u32 p) { return __uint_as_float(p << 16); }
__device__ __forceinline__ float bfhi(u32 p) { return __uint_as_float(p & 0xffff0000u); }
__device__ __forceinline__ float sigmoidf_(float x) { return 1.f / (1.f + __expf(-x)); }

__device__ __forceinline__ void gld16(const void* g, void* l) {
  __builtin_amdgcn_global_load_lds(
      (const __attribute__((address_space(1))) void*)g,
      (__attribute__((address_space(3))) void*)l, 16, 0, 0);
}

// stage a 128-row tile (CPR 16B-chunks per row) global->LDS, contiguous in LDS
template <int CPR, int TOTAL>
__device__ __forceinline__ void stage_tile(const char* gbase, int ld_bytes, char* lds, int tid) {
#pragma unroll
  for (int c = tid; c < TOTAL; c += 256) {
    int row = c / CPR;
    int col = c - row * CPR;
    gld16(gbase + (size_t)row * ld_bytes + (size_t)col * 16, lds + (size_t)c * 16);
  }
}

// ---------- kernel 0: cast weights to bf16 ----------
// wb layout: [0]=Wl [1]=Wlg [2]=Wr [3]=Wrg [4]=Wog [5]=Wout, each 128x128 row-major (K-contig)
__global__ __launch_bounds__(256) void k_prep(
    const float* __restrict__ wl, const float* __restrict__ wlg,
    const float* __restrict__ wr, const float* __restrict__ wrg,
    const float* __restrict__ wog, const float* __restrict__ wout,
    u16* __restrict__ wb) {
  int i = blockIdx.x * 256 + threadIdx.x;   // < 6*16384 exactly
  int m = i >> 14, o = i & 16383;
  const float* src = (m == 0) ? wl : (m == 1) ? wlg : (m == 2) ? wr
                   : (m == 3) ? wrg : (m == 4) ? wog : wout;
  wb[i] = f2bf(src[o]);
}

// ---------- fused LN + 5-projection kernel ----------
// per-k-step GEMM core: b-frags from swizzled LDS Xs, A-frags directly from
// global W (L2-resident, identical across blocks). If Wg != nullptr also
// accumulates the gate GEMM sharing the same b-frags.
__device__ __forceinline__ void proj_k128(
    const u16* __restrict__ Wm, const u16* __restrict__ Wg,
    const u16* Xs, int wr, int wc, int quad, int lq,
    f32x4 acc0[4][4], f32x4 acc1[4][4]) {
#pragma unroll
  for (int ks = 0; ks < 4; ++ks) {
    const int kc = ks * 4 + quad;          // 16B chunk col 0..15
    bf16x8 b[4], am[4], ag[4];
#pragma unroll
    for (int ni = 0; ni < 4; ++ni) {
      const int br = wc * 64 + ni * 16 + lq;
      b[ni] = *(const bf16x8*)((const char*)Xs + br * 256 + ((kc ^ (br & 15)) << 4));
    }
#pragma unroll
    for (int mi = 0; mi < 4; ++mi) {
      const int ar = wr * 64 + mi * 16 + lq;
      am[mi] = *(const bf16x8*)&Wm[(size_t)ar * D_ + kc * 8];
      if (Wg) ag[mi] = *(const bf16x8*)&Wg[(size_t)ar * D_ + kc * 8];
    }
#pragma unroll
    for (int mi = 0; mi < 4; ++mi)
#pragma unroll
      for (int ni = 0; ni < 4; ++ni) {
        acc0[mi][ni] = __builtin_amdgcn_mfma_f32_16x16x32_bf16(am[mi], b[ni], acc0[mi][ni], 0, 0, 0);
        if (Wg)
          acc1[mi][ni] = __builtin_amdgcn_mfma_f32_16x16x32_bf16(ag[mi], b[ni], acc1[mi][ni], 0, 0, 0);
      }
  }
}

__global__ __launch_bounds__(256, 2) void k_lnproj(
    const float* __restrict__ x, const float* __restrict__ mask,
    const float* __restrict__ ng, const float* __restrict__ nb,
    const u16* __restrict__ wb, u16* __restrict__ left_t,
    u16* __restrict__ right_t, u16* __restrict__ gate_t) {
  // Xs: 128x128 bf16, XOR-swizzled at 16B-chunk granularity:
  //   logical (row, chunk c) lives at byte row*256 + (c ^ (row&15))*16
  __shared__ u16 Xs[128 * 128];
  const int tid = threadIdx.x, w = tid >> 6, l = tid & 63;
  const int r0 = blockIdx.x * 128;
  const int half = l >> 5, lh = l & 31;

  // ---- phase 0: LayerNorm(x rows r0..r0+127) -> Xs (bf16, swizzled) ----
  // wave handles 2 rows/iter: lanes 0-31 row A, lanes 32-63 row B, float4 each
  {
    const float4 gg = ((const float4*)ng)[lh];
    const float4 bb = ((const float4*)nb)[lh];
#pragma unroll 4
    for (int it = 0; it < 16; ++it) {
      const int rr = it * 8 + w * 2 + half;   // 0..127, each once
      float4 v = ((const float4*)(x + (size_t)(r0 + rr) * D_))[lh];
      float s = v.x + v.y + v.z + v.w;
      float q = v.x * v.x + v.y * v.y + v.z * v.z + v.w * v.w;
#pragma unroll
      for (int off = 16; off >= 1; off >>= 1) {   // stays within 32-lane half
        s += __shfl_xor(s, off);
        q += __shfl_xor(q, off);
      }
      const float mu  = s * (1.f / 128.f);
      const float var = q * (1.f / 128.f) - mu * mu;
      const float rs  = rsqrtf(var + LN_EPS);
      const u32 p0 = (u32)f2bf((v.x - mu) * rs * gg.x + bb.x)
                   | ((u32)f2bf((v.y - mu) * rs * gg.y + bb.y) << 16);
      const u32 p1 = (u32)f2bf((v.z - mu) * rs * gg.z + bb.z)
                   | ((u32)f2bf((v.w - mu) * rs * gg.w + bb.w) << 16);
      // lane lh holds cols 4lh..4lh+3 -> chunk lh>>1, 8B half lh&1
      u32* d = (u32*)((char*)Xs + rr * 256 + ((((lh >> 1)) ^ (rr & 15)) << 4) + ((lh & 1) << 3));
      d[0] = p0;
      d[1] = p1;
    }
  }
  __syncthreads();   // the only barrier; Xs is read-only below

  const int wr = w >> 1, wc = w & 1, quad = l >> 4, lq = l & 15;
  const f32x4 vz = {0.f, 0.f, 0.f, 0.f};
  f32x4 acc0[4][4], acc1[4][4];

  // ---- phases 1,2: (Wl, Wlg) -> left_t ; (Wr, Wrg) -> right_t ----
#pragma unroll
  for (int g = 0; g < 2; ++g) {
    const u16* Wm = wb + (size_t)(2 * g) * (H_ * D_);
    const u16* Wg = wb + (size_t)(2 * g + 1) * (H_ * D_);
    u16* dst = g ? right_t : left_t;
#pragma unroll
    for (int i = 0; i < 4; ++i)
#pragma unroll
      for (int j = 0; j < 4; ++j) { acc0[i][j] = vz; acc1[i][j] = vz; }

    proj_k128(Wm, Wg, Xs, wr, wc, quad, lq, acc0, acc1);

#pragma unroll
    for (int ni = 0; ni < 4; ++ni) {
      const int r = r0 + wc * 64 + ni * 16 + lq;
      const float mk = mask[r];
#pragma unroll
      for (int mi = 0; mi < 4; ++mi)
#pragma unroll
        for (int reg = 0; reg < 4; ++reg) {
          const int hrow = wr * 64 + mi * 16 + quad * 4 + reg;
          dst[(size_t)hrow * NPOS_ + r] =
              f2bf(acc0[mi][ni][reg] * mk * sigmoidf_(acc1[mi][ni][reg]));
        }
    }
  }

  // ---- phase 3: sigmoid(Wog) -> gate_t ----
#pragma unroll
  for (int i = 0; i < 4; ++i)
#pragma unroll
    for (int j = 0; j < 4; ++j) acc0[i][j] = vz;

  proj_k128(wb + (size_t)4 * (H_ * D_), (const u16*)nullptr, Xs, wr, wc, quad, lq, acc0, acc1);

#pragma unroll
  for (int ni = 0; ni < 4; ++ni) {
    const int r = r0 + wc * 64 + ni * 16 + lq;
#pragma unroll
    for (int mi = 0; mi < 4; ++mi)
#pragma unroll
      for (int reg = 0; reg < 4; ++reg) {
        const int hrow = wr * 64 + mi * 16 + quad * 4 + reg;
        gate_t[(size_t)hrow * NPOS_ + r] = f2bf(sigmoidf_(acc0[mi][ni][reg]));
      }
  }
}

// ---------- kernel 3: per-channel einsum GEMM ----------
// out_t[d][i*512+j] = sum_k left_t[d][i*512+k] * right_t[d][j*512+k]
__global__ __launch_bounds__(256, 2) void k_einsum(
    const u16* __restrict__ left_t, const u16* __restrict__ right_t,
    u16* __restrict__ out_t) {
  const int d = blockIdx.x;         // channel; x-fastest => XCD = d%8 locality
  const int t = blockIdx.y;         // 0..15 -> 4x4 (i,j) tiles
  const int i0 = (t >> 2) * 128, j0 = (t & 3) * 128;
  __shared__ u16 As[128 * 64], Bs[128 * 64];
  const u16* L = left_t + (size_t)d * NPOS_;
  const u16* R = right_t + (size_t)d * NPOS_;
  const int tid = threadIdx.x;
  const int w = tid >> 6, l = tid & 63;
  const int wr = w >> 1, wc = w & 1;

  const f32x4 vz = {0.f, 0.f, 0.f, 0.f};
  f32x4 acc[4][4];
#pragma unroll
  for (int i = 0; i < 4; ++i)
#pragma unroll
    for (int j = 0; j < 4; ++j) acc[i][j] = vz;

  for (int kt = 0; kt < 8; ++kt) {
    stage_tile<8, 1024>((const char*)L + ((size_t)i0 * S_ + kt * 64) * 2, S_ * 2, (char*)As, tid);
    stage_tile<8, 1024>((const char*)R + ((size_t)j0 * S_ + kt * 64) * 2, S_ * 2, (char*)Bs, tid);
    __syncthreads();
#pragma unroll
    for (int kk = 0; kk < 2; ++kk) {
      const int ko = kk * 32 + (l >> 4) * 8;
      bf16x8 a[4], b[4];
#pragma unroll
      for (int mi = 0; mi < 4; ++mi)
        a[mi] = *(const bf16x8*)&As[(wr * 64 + mi * 16 + (l & 15)) * 64 + ko];
#pragma unroll
      for (int ni = 0; ni < 4; ++ni)
        b[ni] = *(const bf16x8*)&Bs[(wc * 64 + ni * 16 + (l & 15)) * 64 + ko];
#pragma unroll
      for (int mi = 0; mi < 4; ++mi)
#pragma unroll
        for (int ni = 0; ni < 4; ++ni)
          acc[mi][ni] = __builtin_amdgcn_mfma_f32_16x16x32_bf16(a[mi], b[ni], acc[mi][ni], 0, 0, 0);
    }
    __syncthreads();
  }

  const int quad = l >> 4, lc = l & 15;
  u16* O = out_t + (size_t)d * NPOS_;
#pragma unroll
  for (int mi = 0; mi < 4; ++mi)
#pragma unroll
    for (int ni = 0; ni < 4; ++ni) {
      const int col = j0 + wc * 64 + ni * 16 + lc;
#pragma unroll
      for (int reg = 0; reg < 4; ++reg) {
        const int row = i0 + wr * 64 + mi * 16 + quad * 4 + reg;
        O[(size_t)row * S_ + col] = f2bf(acc[mi][ni][reg]);
      }
    }
}

// ---------- kernel 4: out-LN over H, gate, @Wout^T ----------
__global__ __launch_bounds__(256, 2) void k_final(
    const u16* __restrict__ out_t, const u16* __restrict__ gate_t,
    const float* __restrict__ og, const float* __restrict__ ob,
    const u16* __restrict__ wout_b, float* __restrict__ out) {
  __shared__ u16 A_lds[128 * 136];   // [position j][h], padded stride
  __shared__ u16 Wlds[128 * 128];    // Wout [dout][h]
  __shared__ float psum[4][128], pq[4][128];
  __shared__ float mu_s[128], rs_s[128];
  const int tid = threadIdx.x, w = tid >> 6, l = tid & 63;
  const int r0 = blockIdx.x * 128;

  stage_tile<16, 2048>((const char*)wout_b, 256, (char*)Wlds, tid);

  // pass 1: stats over channels, lane owns positions 2l, 2l+1
  float s0 = 0.f, s1 = 0.f, q0 = 0.f, q1 = 0.f;
  for (int it = 0; it < 32; ++it) {
    int d = it * 4 + w;
    u32 p = *(const u32*)&out_t[(size_t)d * NPOS_ + r0 + 2 * l];
    float f0 = bflo(p), f1 = bfhi(p);
    s0 += f0; s1 += f1; q0 += f0 * f0; q1 += f1 * f1;
  }
  psum[w][2 * l] = s0; psum[w][2 * l + 1] = s1;
  pq[w][2 * l] = q0;   pq[w][2 * l + 1] = q1;
  __syncthreads();
  if (tid < 128) {
    float s = psum[0][tid] + psum[1][tid] + psum[2][tid] + psum[3][tid];
    float q = pq[0][tid] + pq[1][tid] + pq[2][tid] + pq[3][tid];
    float mu  = s * (1.f / 128.f);
    float var = q * (1.f / 128.f) - mu * mu;
    mu_s[tid] = mu;
    rs_s[tid] = rsqrtf(var + LN_EPS);
  }
  __syncthreads();

  // pass 2 (L2-hot reload): normalize*gate -> bf16 A tile [j][h]
  for (int it = 0; it < 32; ++it) {
    int d = it * 4 + w;
    u32 p  = *(const u32*)&out_t[(size_t)d * NPOS_ + r0 + 2 * l];
    u32 gp = *(const u32*)&gate_t[(size_t)d * NPOS_ + r0 + 2 * l];
    float gd = og[d], bd = ob[d];
    float f0 = bflo(p), f1 = bfhi(p);
    float g0 = bflo(gp), g1 = bfhi(gp);
    int ja = 2 * l, jb = 2 * l + 1;
    float a0 = ((f0 - mu_s[ja]) * rs_s[ja] * gd + bd) * g0;
    float a1 = ((f1 - mu_s[jb]) * rs_s[jb] * gd + bd) * g1;
    A_lds[(size_t)ja * 136 + d] = f2bf(a0);
    A_lds[(size_t)jb * 136 + d] = f2bf(a1);
  }
  __syncthreads();

  // GEMM: out[r0+j][dout] = sum_h A[j][h] * Wout[dout][h]
  const int wr = w >> 1, wc = w & 1;
  const f32x4 vz = {0.f, 0.f, 0.f, 0.f};
  f32x4 acc[4][4];
#pragma unroll
  for (int i = 0; i < 4; ++i)
#pragma unroll
    for (int j = 0; j < 4; ++j) acc[i][j] = vz;
#pragma unroll
  for (int kk = 0; kk < 4; ++kk) {
    const int ko = kk * 32 + (l >> 4) * 8;
    bf16x8 a[4], b[4];
#pragma unroll
    for (int mi = 0; mi < 4; ++mi)
      a[mi] = *(const bf16x8*)&A_lds[(wr * 64 + mi * 16 + (l & 15)) * 136 + ko];
#pragma unroll
    for (int ni = 0; ni < 4; ++ni)
      b[ni] = *(const bf16x8*)&Wlds[(wc * 64 + ni * 16 + (l & 15)) * 128 + ko];
#pragma unroll
    for (int mi = 0; mi < 4; ++mi)
#pragma unroll
      for (int ni = 0; ni < 4; ++ni)
        acc[mi][ni] = __builtin_amdgcn_mfma_f32_16x16x32_bf16(a[mi], b[ni], acc[mi][ni], 0, 0, 0);
  }
  const int quad = l >> 4, lc = l & 15;
#pragma unroll
  for (int mi = 0; mi < 4; ++mi)
#pragma unroll
    for (int ni = 0; ni < 4; ++ni) {
      const int dout = wc * 64 + ni * 16 + lc;
#pragma unroll
      for (int reg = 0; reg < 4; ++reg) {
        const int row = r0 + wr * 64 + mi * 16 + quad * 4 + reg;
        out[(size_t)row * D_ + dout] = acc[mi][ni][reg];
      }
    }
}

// ---------- launcher ----------
extern "C" void kernel_launch(void* const* d_in, const int* in_sizes, int n_in,
                              void* d_out, int out_size, void* d_ws, size_t ws_size,
                              hipStream_t stream) {
  const float* x    = (const float*)d_in[0];
  const float* mask = (const float*)d_in[1];
  const float* ng   = (const float*)d_in[2];
  const float* nb   = (const float*)d_in[3];
  const float* Wl   = (const float*)d_in[4];
  const float* Wr   = (const float*)d_in[5];
  const float* Wlg  = (const float*)d_in[6];
  const float* Wrg  = (const float*)d_in[7];
  const float* Wog  = (const float*)d_in[8];
  const float* og   = (const float*)d_in[9];
  const float* ob   = (const float*)d_in[10];
  const float* Wout = (const float*)d_in[11];
  float* out = (float*)d_out;

  // workspace layout (bytes): out_t reuses slab 0 (xn no longer exists)
  const size_t SLAB = (size_t)NPOS_ * H_ * 2;  // 67,108,864
  char* ws = (char*)d_ws;
  u16* left_t  = (u16*)(ws + SLAB);
  u16* right_t = (u16*)(ws + 2 * SLAB);
  u16* gate_t  = (u16*)(ws + 3 * SLAB);
  u16* wb      = (u16*)(ws + 4 * SLAB);        // 6*128*128 bf16 = 196,608 B
  u16* out_t   = (u16*)(ws);                   // slab 0
  if (ws_size < 4 * SLAB + 6 * H_ * D_ * sizeof(u16)) return;  // visible failure mode

  k_prep<<<384, 256, 0, stream>>>(Wl, Wlg, Wr, Wrg, Wog, Wout, wb);
  k_lnproj<<<2048, 256, 0, stream>>>(x, mask, ng, nb, wb, left_t, right_t, gate_t);
  k_einsum<<<dim3(128, 16), 256, 0, stream>>>(left_t, right_t, out_t);
  k_final<<<2048, 256, 0, stream>>>(out_t, gate_t, og, ob, wb + 5 * H_ * D_, out);
}